// Round 1
// baseline (4265.852 us; speedup 1.0000x reference)
//
#include <hip/hip_runtime.h>
#include <hip/hip_fp16.h>

typedef _Float16 f16;
typedef _Float16 f16x8 __attribute__((ext_vector_type(8)));
typedef _Float16 f16x4 __attribute__((ext_vector_type(4)));
typedef float    f32x4 __attribute__((ext_vector_type(4)));

#define TT 512
#define BB 256
#define HH 256

// ---- workspace byte offsets (fixed region) ----
#define O_WFRAG_ENC 0u
#define O_WFRAG_M   393216u
#define O_WFRAG_P   786432u
#define O_WFRAG_GI  1179648u
#define O_HE_ST     1966080u
#define O_HM_ST     2097152u
#define O_HP_ST     2228224u
#define O_HPSUM     2359296u
#define O_DYN       2621440u
// per-slice-step dynamic bytes: he_buf 131072 + gi_buf 786432
#define DYN_PER_STEP 917504u

__device__ __forceinline__ float sigf(float x){ return 1.0f/(1.0f+__expf(-x)); }
__device__ __forceinline__ float tanh_(float x){
  float xc = fminf(fmaxf(x,-15.f),15.f);
  float e  = __expf(2.f*xc);
  return (e-1.f)/(e+1.f);
}
// XOR-swizzled element index into a [16][256] f16 tile (16B granules ^ row&7)
__device__ __forceinline__ int hswz(int row, int j){
  return row*256 + ((((j>>3) ^ (row&7)))<<3) + (j&7);
}

// =====================================================================
// PREP: convert f32 weights -> f16 fragment-ordered buffers, init states
// total items = 3*196608 + 393216 + 65536 = 1048576 (grid 4096*256 exact)
// =====================================================================
__global__ void prep_kernel(
    const float* __restrict__ enc_whh, const float* __restrict__ mdec_whh,
    const float* __restrict__ pdec_whh, const float* __restrict__ mdec_wih,
    const float* __restrict__ pdec_wih,
    const float* __restrict__ h0e, const float* __restrict__ h0m, const float* __restrict__ h0p,
    f16* __restrict__ wfrag_enc, f16* __restrict__ wfrag_m, f16* __restrict__ wfrag_p,
    f16* __restrict__ wfrag_gi,
    f16* __restrict__ he_st, f16* __restrict__ hm_st, f16* __restrict__ hp_st,
    float* __restrict__ hpsum)
{
  int idx = blockIdx.x*256 + threadIdx.x;
  const int NW = 16*3*8*64*8; // 196608 per recurrence buffer
  if (idx < 3*NW){
    int b = idx / NW, e = idx % NW;
    int jj = e & 7, l = (e>>3)&63, ks = (e>>9)&7, t2 = e>>12;
    int g = t2 % 3, w = t2 / 3;                 // w = j-block 0..15
    int row = g*256 + w*16 + (l&15);            // gate row of W_hh
    int col = ks*32 + (l>>4)*8 + jj;            // k index
    const float* W = (b==0)?enc_whh:((b==1)?mdec_whh:pdec_whh);
    f16* D = (b==0)?wfrag_enc:((b==1)?wfrag_m:wfrag_p);
    D[e] = (f16)W[row*256+col];
    return;
  }
  idx -= 3*NW;
  const int NG = 96*8*64*8; // 393216 : concat [mdec_wih; pdec_wih] fragments
  if (idx < NG){
    int e = idx;
    int jj = e&7, l=(e>>3)&63, ks=(e>>9)&7, mt = e>>12; // mt 0..95
    int row = mt*16 + (l&15);                   // 0..1535
    int col = ks*32 + (l>>4)*8 + jj;
    float v = (row < 768) ? mdec_wih[row*256+col] : pdec_wih[(row-768)*256+col];
    wfrag_gi[e] = (f16)v;
    return;
  }
  idx -= NG;
  if (idx < 65536){
    he_st[idx] = (f16)h0e[idx];
    hm_st[idx] = (f16)h0m[idx];
    hp_st[idx] = (f16)h0p[idx];
    hpsum[idx] = 0.f;
  }
}

// =====================================================================
// Recurrence core. MODE 0=encoder, 1=mask-decoder, 2=pred-decoder.
// One 256-thread WG per 16-row batch tile; full W_hh register-resident
// as MFMA B-fragments (96 x f16x8). h kept in LDS (swizzled), double-buffered.
// =====================================================================
template<int MODE>
__device__ __forceinline__ void gru_run(
  int bt, int slice, int SL,
  const f16* __restrict__ wfrag,
  const float* __restrict__ bih, const float* __restrict__ bhh,
  const float* __restrict__ enc_wih,
  const float* __restrict__ seq, const float* __restrict__ dpad,
  const f16* __restrict__ gi_src,      // pre-offset for (bt, rec)
  f16* __restrict__ h_state,
  f16* __restrict__ he_buf,
  const float* __restrict__ mlin_w, const float* __restrict__ mlin_b,
  float* __restrict__ out_mask,
  float* __restrict__ hpsum,
  unsigned char* smem)
{
  const int tid = threadIdx.x;       // 256
  const int lane = tid & 63;
  const int wid  = tid >> 6;         // 0..3
  const int l15  = lane & 15;
  const int lhi  = lane >> 4;        // 0..3
  const int bi0  = lhi*4;
  const int b0   = bt*16;

  f16* hbuf  = (f16*)smem;                               // [2][16*256] swizzled
  f16* gib   = (f16*)(smem + 2*16*256*2);                // [2][12288]
  float* xb  = (float*)(smem + 2*16*256*2 + 2*12288*2);  // [2][16]
  float* mred = xb + 32;                                 // [2][4 waves][16 rows]

  // ---- resident B-fragments: wf[q][gate][kstep], q -> j-block wid*4+q
  f16x8 wf[4][3][8];
  #pragma unroll
  for (int q=0;q<4;++q){
    const int w = wid*4+q;
    #pragma unroll
    for (int g=0;g<3;++g)
      #pragma unroll
      for (int ks=0;ks<8;++ks)
        wf[q][g][ks] = *(const f16x8*)(wfrag + ((size_t)(((w*3+g)*8)+ks)*64 + lane)*8);
  }
  // ---- per-lane fused biases (r,z merged in/out; n keeps bih separate)
  float cr[4], cz[4], cnh[4], cni[4];
  float wr_[4], wz_[4], wn_[4], mw[4];
  #pragma unroll
  for (int q=0;q<4;++q){
    const int j = (wid*4+q)*16 + l15;
    cr[q]  = bih[j]     + bhh[j];
    cz[q]  = bih[256+j] + bhh[256+j];
    cnh[q] = bhh[512+j];
    cni[q] = bih[512+j];
    if (MODE==0){ wr_[q]=enc_wih[j]; wz_[q]=enc_wih[256+j]; wn_[q]=enc_wih[512+j]; }
    if (MODE==1){ mw[q]=mlin_w[j]; }
  }
  // ---- initial h state -> hbuf[0]
  #pragma unroll
  for (int q=0;q<4;++q){
    const int j = (wid*4+q)*16 + l15;
    #pragma unroll
    for (int r=0;r<4;++r)
      hbuf[hswz(bi0+r, j)] = h_state[(size_t)(b0+bi0+r)*256 + j];
  }
  if (MODE==0){
    if (tid<16){
      const int t = slice*SL;
      xb[tid] = (t==0) ? dpad[b0+tid] : seq[(size_t)(t-1)*BB + b0 + tid];
    }
  } else {
    const uint4* g0 = (const uint4*)gi_src;        // ts=0 block (24KB)
    uint4* d = (uint4*)gib;
    #pragma unroll
    for (int k=0;k<6;++k) d[tid + k*256] = g0[tid + k*256];
  }
  __syncthreads();

  float psum[4][4];
  if (MODE==2){
    #pragma unroll
    for (int q=0;q<4;++q)
      #pragma unroll
      for (int r=0;r<4;++r) psum[q][r]=0.f;
  }

  for (int ts=0; ts<SL; ++ts){
    const int cur = ts & 1;
    f16* hc = hbuf + cur*4096;
    f16* hn = hbuf + (cur^1)*4096;

    // stage next-step inputs (latency hidden under MFMA/gates)
    uint4 pf0,pf1,pf2,pf3,pf4,pf5;
    if (MODE==0){
      if (tid<16 && ts+1<SL){
        const int t = slice*SL + ts + 1;   // >=1 always
        xb[(cur^1)*16 + tid] = seq[(size_t)(t-1)*BB + b0 + tid];
      }
    } else {
      if (ts+1 < SL){
        const uint4* gn = (const uint4*)((const char*)gi_src + (size_t)(ts+1)*786432u);
        pf0 = gn[tid];       pf1 = gn[tid+256];  pf2 = gn[tid+512];
        pf3 = gn[tid+768];   pf4 = gn[tid+1024]; pf5 = gn[tid+1280];
      }
    }
    // mask output for previous step (reads other buffer of mred; race-free)
    if (MODE==1){
      if (tid<16 && ts>0){
        float v = mlin_b[0];
        #pragma unroll
        for (int w=0;w<4;++w) v += mred[(cur^1)*64 + w*16 + tid];
        out_mask[(size_t)(slice*SL + ts-1)*BB + b0 + tid] = v;
      }
    }

    float mpart[4] = {0.f,0.f,0.f,0.f};
    #pragma unroll
    for (int q=0;q<4;++q){
      const int j = (wid*4+q)*16 + l15;
      f32x4 a0 = {cr[q],cr[q],cr[q],cr[q]};
      f32x4 a1 = {cz[q],cz[q],cz[q],cz[q]};
      f32x4 a2 = {cnh[q],cnh[q],cnh[q],cnh[q]};
      #pragma unroll
      for (int ks=0;ks<8;++ks){
        const f16x8 a = *(const f16x8*)(hc + l15*256 + ((((ks*4+lhi) ^ (l15&7)))<<3));
        a0 = __builtin_amdgcn_mfma_f32_16x16x32_f16(a, wf[q][0][ks], a0, 0,0,0);
        a1 = __builtin_amdgcn_mfma_f32_16x16x32_f16(a, wf[q][1][ks], a1, 0,0,0);
        a2 = __builtin_amdgcn_mfma_f32_16x16x32_f16(a, wf[q][2][ks], a2, 0,0,0);
      }
      float gir[4], giz[4], gin[4];
      if (MODE==0){
        #pragma unroll
        for (int r=0;r<4;++r){
          const float x = xb[cur*16 + bi0 + r];
          gir[r]=x*wr_[q]; giz[r]=x*wz_[q]; gin[r]=x*wn_[q];
        }
      } else {
        const f16* gb = gib + cur*12288;
        const f16x4 g0v = *(const f16x4*)(gb + j*16 + bi0);
        const f16x4 g1v = *(const f16x4*)(gb + (256+j)*16 + bi0);
        const f16x4 g2v = *(const f16x4*)(gb + (512+j)*16 + bi0);
        #pragma unroll
        for (int r=0;r<4;++r){ gir[r]=(float)g0v[r]; giz[r]=(float)g1v[r]; gin[r]=(float)g2v[r]; }
      }
      #pragma unroll
      for (int r=0;r<4;++r){
        const int sz = hswz(bi0+r, j);
        const float hprev = (float)hc[sz];
        const float rr = sigf(gir[r] + a0[r]);
        const float zz = sigf(giz[r] + a1[r]);
        const float nn = tanh_(gin[r] + cni[q] + rr*a2[r]);
        const float h  = (1.f-zz)*nn + zz*hprev;
        hn[sz] = (f16)h;
        if (MODE==0) he_buf[((size_t)ts*BB + (b0+bi0+r))*HH + j] = (f16)h;
        if (MODE==1) mpart[r] += h*mw[q];
        if (MODE==2) psum[q][r] += h;
      }
    }
    if (MODE==1){
      #pragma unroll
      for (int m=1;m<16;m<<=1){
        #pragma unroll
        for (int r=0;r<4;++r) mpart[r] += __shfl_xor(mpart[r], m, 64);
      }
      if (l15==0){
        #pragma unroll
        for (int r=0;r<4;++r) mred[cur*64 + wid*16 + bi0 + r] = mpart[r];
      }
    }
    if (MODE!=0){
      if (ts+1 < SL){
        uint4* dn = (uint4*)(gib + (cur^1)*12288);
        dn[tid]=pf0; dn[tid+256]=pf1; dn[tid+512]=pf2;
        dn[tid+768]=pf3; dn[tid+1024]=pf4; dn[tid+1280]=pf5;
      }
    }
    __syncthreads();
  }

  // final mask row
  if (MODE==1 && tid<16){
    float v = mlin_b[0];
    #pragma unroll
    for (int w=0;w<4;++w) v += mred[((SL-1)&1)*64 + w*16 + tid];
    out_mask[(size_t)(slice*SL + SL-1)*BB + b0 + tid] = v;
  }
  // h state writeback from final buffer
  {
    const f16* hf = hbuf + (SL&1)*4096;
    #pragma unroll
    for (int q=0;q<4;++q){
      const int j = (wid*4+q)*16 + l15;
      #pragma unroll
      for (int r=0;r<4;++r)
        h_state[(size_t)(b0+bi0+r)*256 + j] = hf[hswz(bi0+r, j)];
    }
  }
  if (MODE==2){
    #pragma unroll
    for (int q=0;q<4;++q){
      const int j = (wid*4+q)*16 + l15;
      #pragma unroll
      for (int r=0;r<4;++r){
        const size_t idx = (size_t)(b0+bi0+r)*256 + j;
        hpsum[idx] = hpsum[idx] + psum[q][r];
      }
    }
  }
}

// combined launcher kernel: blocks [0,n_dec) = decoders (16 mdec + 16 pdec),
// blocks [n_dec, n_dec+16) = encoder for slice enc_slice.
__global__ __launch_bounds__(256,1) void rec_kernel(
  const float* __restrict__ seq, const float* __restrict__ dpad,
  const float* __restrict__ enc_wih, const float* __restrict__ enc_bih, const float* __restrict__ enc_bhh,
  const float* __restrict__ mdec_bih, const float* __restrict__ mdec_bhh,
  const float* __restrict__ pdec_bih, const float* __restrict__ pdec_bhh,
  const float* __restrict__ mlin_w, const float* __restrict__ mlin_b,
  const f16* __restrict__ wfrag_enc, const f16* __restrict__ wfrag_m, const f16* __restrict__ wfrag_p,
  f16* __restrict__ he_st, f16* __restrict__ hm_st, f16* __restrict__ hp_st,
  f16* __restrict__ he_buf, const f16* __restrict__ gi_buf,
  float* __restrict__ hpsum, float* __restrict__ out_mask,
  int dec_slice, int enc_slice, int n_dec, int SL)
{
  __shared__ __align__(16) unsigned char smem[2*16*256*2 + 2*12288*2 + (32+128)*4];
  const int bid = blockIdx.x;
  if (bid < n_dec){
    const int rec = bid >> 4, bt = bid & 15;
    const f16* gsrc = gi_buf + ((size_t)bt*1536 + (size_t)rec*768)*16;
    if (rec==0)
      gru_run<1>(bt, dec_slice, SL, wfrag_m, mdec_bih, mdec_bhh, nullptr, nullptr, nullptr,
                 gsrc, hm_st, nullptr, mlin_w, mlin_b, out_mask, nullptr, smem);
    else
      gru_run<2>(bt, dec_slice, SL, wfrag_p, pdec_bih, pdec_bhh, nullptr, nullptr, nullptr,
                 gsrc, hp_st, nullptr, nullptr, nullptr, nullptr, hpsum, smem);
  } else {
    const int bt = bid - n_dec;
    gru_run<0>(bt, enc_slice, SL, wfrag_enc, enc_bih, enc_bhh, enc_wih, seq, dpad,
               nullptr, he_st, he_buf, nullptr, nullptr, nullptr, nullptr, smem);
  }
}

// =====================================================================
// GI: gi[t][b][n] = he[t][b][:] . w_ih_cat[n][:]  (both decoders, n<768 mdec)
// grid = SL*4 blocks (ts, batch-quarter), 256 threads
// =====================================================================
__global__ __launch_bounds__(256,4) void gi_kernel(
  const f16* __restrict__ he_buf, const f16* __restrict__ wfrag_gi,
  f16* __restrict__ gi_buf)
{
  const int ts = blockIdx.x >> 2;
  const int bq = blockIdx.x & 3;
  const int tid = threadIdx.x, lane = tid&63, wid = tid>>6;
  const int l15 = lane&15, lhi = lane>>4;
  __shared__ f16 het[64*264];
  {
    const uint4* src = (const uint4*)(he_buf + ((size_t)ts*BB + bq*64)*HH);
    uint4* dst = (uint4*)het;
    #pragma unroll
    for (int k=0;k<8;++k){
      const int i = tid + k*256;                 // 2048 uint4 = 64 rows x 32
      dst[(i>>5)*33 + (i&31)] = src[i];
    }
  }
  __syncthreads();
  for (int mi=0; mi<24; ++mi){
    const int mt = wid*24 + mi;
    f32x4 acc[4] = {{0,0,0,0},{0,0,0,0},{0,0,0,0},{0,0,0,0}};
    #pragma unroll
    for (int ks=0;ks<8;++ks){
      const f16x8 a = *(const f16x8*)(wfrag_gi + ((size_t)(mt*8+ks)*64 + lane)*8);
      #pragma unroll
      for (int bt=0;bt<4;++bt){
        const f16x8 b = *(const f16x8*)(het + (bt*16+l15)*264 + ks*32 + lhi*8);
        acc[bt] = __builtin_amdgcn_mfma_f32_16x16x32_f16(a, b, acc[bt], 0,0,0);
      }
    }
    #pragma unroll
    for (int bt=0;bt<4;++bt){
      const int btg = bq*4 + bt;
      const size_t base = (((size_t)ts*16 + btg)*1536 + (size_t)mt*16 + lhi*4)*16 + l15;
      #pragma unroll
      for (int r=0;r<4;++r) gi_buf[base + (size_t)r*16] = (f16)acc[bt][r];
    }
  }
}

// =====================================================================
// PRED: pred[b][p] = (hpsum[b]/512) . plin_w[p] + plin_b[p]
// =====================================================================
__global__ __launch_bounds__(256,1) void pred_kernel(
  const float* __restrict__ hpsum, const float* __restrict__ plin_w,
  const float* __restrict__ plin_b, float* __restrict__ out)
{
  __shared__ float hs[256];
  const int p = threadIdx.x;
  const float bias = plin_b[p];
  for (int bb=0; bb<4; ++bb){
    const int b = blockIdx.x*4 + bb;
    __syncthreads();
    hs[p] = hpsum[(size_t)b*256 + p];
    __syncthreads();
    float acc = 0.f;
    const float4* wrow = (const float4*)(plin_w + (size_t)p*256);
    #pragma unroll 4
    for (int k4=0;k4<64;++k4){
      const float4 w = wrow[k4];
      acc += hs[k4*4+0]*w.x + hs[k4*4+1]*w.y + hs[k4*4+2]*w.z + hs[k4*4+3]*w.w;
    }
    out[131072 + (size_t)b*256 + p] = acc*(1.f/512.f) + bias;
  }
}

// =====================================================================
extern "C" void kernel_launch(void* const* d_in, const int* in_sizes, int n_in,
                              void* d_out, int out_size, void* d_ws, size_t ws_size,
                              hipStream_t stream)
{
  const float* seq      = (const float*)d_in[0];
  const float* dpad     = (const float*)d_in[1];
  const float* h0e      = (const float*)d_in[2];
  const float* h0m      = (const float*)d_in[3];
  const float* h0p      = (const float*)d_in[4];
  const float* enc_wih  = (const float*)d_in[5];
  const float* enc_whh  = (const float*)d_in[6];
  const float* enc_bih  = (const float*)d_in[7];
  const float* enc_bhh  = (const float*)d_in[8];
  const float* mdec_wih = (const float*)d_in[9];
  const float* mdec_whh = (const float*)d_in[10];
  const float* mdec_bih = (const float*)d_in[11];
  const float* mdec_bhh = (const float*)d_in[12];
  const float* mlin_w   = (const float*)d_in[13];
  const float* mlin_b   = (const float*)d_in[14];
  const float* pdec_wih = (const float*)d_in[15];
  const float* pdec_whh = (const float*)d_in[16];
  const float* pdec_bih = (const float*)d_in[17];
  const float* pdec_bhh = (const float*)d_in[18];
  const float* plin_w   = (const float*)d_in[19];
  const float* plin_b   = (const float*)d_in[20];
  float* out = (float*)d_out;

  char* ws = (char*)d_ws;
  f16* wfrag_enc = (f16*)(ws + O_WFRAG_ENC);
  f16* wfrag_m   = (f16*)(ws + O_WFRAG_M);
  f16* wfrag_p   = (f16*)(ws + O_WFRAG_P);
  f16* wfrag_gi  = (f16*)(ws + O_WFRAG_GI);
  f16* he_st     = (f16*)(ws + O_HE_ST);
  f16* hm_st     = (f16*)(ws + O_HM_ST);
  f16* hp_st     = (f16*)(ws + O_HP_ST);
  float* hpsum   = (float*)(ws + O_HPSUM);

  int SL = 64;  // time-slice length; shrink to fit workspace
  while (SL > 1 && (size_t)O_DYN + (size_t)SL*DYN_PER_STEP > ws_size) SL >>= 1;
  const int S = TT / SL;
  f16* he_buf = (f16*)(ws + O_DYN);
  f16* gi_buf = (f16*)(ws + O_DYN + (size_t)SL*131072u);

  prep_kernel<<<dim3(4096), dim3(256), 0, stream>>>(
      enc_whh, mdec_whh, pdec_whh, mdec_wih, pdec_wih, h0e, h0m, h0p,
      wfrag_enc, wfrag_m, wfrag_p, wfrag_gi, he_st, hm_st, hp_st, hpsum);

  // encoder slice 0 (no decoders yet)
  rec_kernel<<<dim3(16), dim3(256), 0, stream>>>(
      seq, dpad, enc_wih, enc_bih, enc_bhh, mdec_bih, mdec_bhh, pdec_bih, pdec_bhh,
      mlin_w, mlin_b, wfrag_enc, wfrag_m, wfrag_p, he_st, hm_st, hp_st,
      he_buf, gi_buf, hpsum, out, 0, 0, 0, SL);
  gi_kernel<<<dim3(SL*4), dim3(256), 0, stream>>>(he_buf, wfrag_gi, gi_buf);

  for (int s=0; s<S; ++s){
    const int has_enc = (s+1 < S);
    rec_kernel<<<dim3(has_enc?48:32), dim3(256), 0, stream>>>(
        seq, dpad, enc_wih, enc_bih, enc_bhh, mdec_bih, mdec_bhh, pdec_bih, pdec_bhh,
        mlin_w, mlin_b, wfrag_enc, wfrag_m, wfrag_p, he_st, hm_st, hp_st,
        he_buf, gi_buf, hpsum, out, s, s+1, 32, SL);
    if (has_enc)
      gi_kernel<<<dim3(SL*4), dim3(256), 0, stream>>>(he_buf, wfrag_gi, gi_buf);
  }

  pred_kernel<<<dim3(64), dim3(256), 0, stream>>>(hpsum, plin_w, plin_b, out);
}

// Round 2
// 3521.431 us; speedup vs baseline: 1.2114x; 1.2114x over previous
//
#include <hip/hip_runtime.h>
#include <hip/hip_fp16.h>

typedef _Float16 f16;
typedef _Float16 f16x8 __attribute__((ext_vector_type(8)));
typedef _Float16 f16x4 __attribute__((ext_vector_type(4)));
typedef float    f32x4 __attribute__((ext_vector_type(4)));

#define TT 512
#define BB 256
#define HH 256

// ---- workspace byte offsets (fixed region) ----
#define O_WFRAG_ENC 0u
#define O_WFRAG_M   393216u
#define O_WFRAG_P   786432u
#define O_WFRAG_GI  1179648u
#define O_HE_ST     1966080u
#define O_HM_ST     2097152u
#define O_HP_ST     2228224u
#define O_HPSUM     2359296u
#define O_DYN       2621440u
// per-slice-step dynamic bytes: he_buf 131072 + gi_buf 786432
#define DYN_PER_STEP 917504u

__device__ __forceinline__ float sigf(float x){ return 1.0f/(1.0f+__expf(-x)); }
__device__ __forceinline__ float tanh_(float x){
  float xc = fminf(fmaxf(x,-15.f),15.f);
  float e  = __expf(2.f*xc);
  return (e-1.f)/(e+1.f);
}
// XOR-swizzled element index into a [16][256] f16 tile (16B granules ^ row&7)
__device__ __forceinline__ int hswz(int row, int j){
  return row*256 + ((((j>>3) ^ (row&7)))<<3) + (j&7);
}
// async global->LDS, 16B per lane (dest = wave-uniform base + lane*16)
__device__ __forceinline__ void gload_lds16(const void* g, void* l){
  __builtin_amdgcn_global_load_lds(
      (const __attribute__((address_space(1))) unsigned int*)g,
      (__attribute__((address_space(3))) unsigned int*)l, 16, 0, 0);
}

// =====================================================================
// PREP: convert f32 weights -> f16 fragment-ordered buffers, init states
// =====================================================================
__global__ void prep_kernel(
    const float* __restrict__ enc_whh, const float* __restrict__ mdec_whh,
    const float* __restrict__ pdec_whh, const float* __restrict__ mdec_wih,
    const float* __restrict__ pdec_wih,
    const float* __restrict__ h0e, const float* __restrict__ h0m, const float* __restrict__ h0p,
    f16* __restrict__ wfrag_enc, f16* __restrict__ wfrag_m, f16* __restrict__ wfrag_p,
    f16* __restrict__ wfrag_gi,
    f16* __restrict__ he_st, f16* __restrict__ hm_st, f16* __restrict__ hp_st,
    float* __restrict__ hpsum)
{
  int idx = blockIdx.x*256 + threadIdx.x;
  const int NW = 16*3*8*64*8; // 196608 per recurrence buffer
  if (idx < 3*NW){
    int b = idx / NW, e = idx % NW;
    int jj = e & 7, l = (e>>3)&63, ks = (e>>9)&7, t2 = e>>12;
    int g = t2 % 3, w = t2 / 3;                 // w = j-block 0..15
    int row = g*256 + w*16 + (l&15);            // gate row of W_hh
    int col = ks*32 + (l>>4)*8 + jj;            // k index
    const float* W = (b==0)?enc_whh:((b==1)?mdec_whh:pdec_whh);
    f16* D = (b==0)?wfrag_enc:((b==1)?wfrag_m:wfrag_p);
    D[e] = (f16)W[row*256+col];
    return;
  }
  idx -= 3*NW;
  const int NG = 96*8*64*8; // 393216 : concat [mdec_wih; pdec_wih] fragments
  if (idx < NG){
    int e = idx;
    int jj = e&7, l=(e>>3)&63, ks=(e>>9)&7, mt = e>>12; // mt 0..95
    int row = mt*16 + (l&15);                   // 0..1535
    int col = ks*32 + (l>>4)*8 + jj;
    float v = (row < 768) ? mdec_wih[row*256+col] : pdec_wih[(row-768)*256+col];
    wfrag_gi[e] = (f16)v;
    return;
  }
  idx -= NG;
  if (idx < 65536){
    he_st[idx] = (f16)h0e[idx];
    hm_st[idx] = (f16)h0m[idx];
    hp_st[idx] = (f16)h0p[idx];
    hpsum[idx] = 0.f;
  }
}

// =====================================================================
// Recurrence core. MODE 0=encoder, 1=mask-decoder, 2=pred-decoder.
// 512 threads (8 waves) per 16-row batch tile. Each wave owns a 32-wide
// j-slice: wf[2][3][8] = 192 VGPRs of resident W_hh fragments (no spill).
// h in LDS (swizzled, double-buffered). Decoder gi staged via
// global_load_lds into the free half of the LDS double buffer (0 VGPRs).
// =====================================================================
template<int MODE>
__device__ __forceinline__ void gru_run(
  int bt, int slice, int SL,
  const f16* __restrict__ wfrag,
  const float* __restrict__ bih, const float* __restrict__ bhh,
  const float* __restrict__ enc_wih,
  const float* __restrict__ seq, const float* __restrict__ dpad,
  const f16* __restrict__ gi_src,      // pre-offset for (bt, rec)
  f16* __restrict__ h_state,
  f16* __restrict__ he_buf,
  const float* __restrict__ mlin_w, const float* __restrict__ mlin_b,
  float* __restrict__ out_mask,
  float* __restrict__ hpsum,
  unsigned char* smem)
{
  const int tid = threadIdx.x;       // 512
  const int lane = tid & 63;
  const int wid  = tid >> 6;         // 0..7
  const int l15  = lane & 15;
  const int lhi  = lane >> 4;        // 0..3
  const int bi0  = lhi*4;
  const int b0   = bt*16;

  f16* hbuf  = (f16*)smem;                        // [2][16*256] swizzled (16 KB)
  f16* gib   = (f16*)(smem + 16384);              // [2][12288]        (48 KB)
  float* xb  = (float*)(smem + 16384 + 49152);    // [2][16]
  float* mred = xb + 32;                          // [2][8 waves][16 rows]

  // ---- resident B-fragments: wf[q][gate][kstep], j-block = wid*2+q
  f16x8 wf[2][3][8];
  #pragma unroll
  for (int q=0;q<2;++q){
    const int w = wid*2+q;
    #pragma unroll
    for (int g=0;g<3;++g)
      #pragma unroll
      for (int ks=0;ks<8;++ks)
        wf[q][g][ks] = *(const f16x8*)(wfrag + ((size_t)(((w*3+g)*8)+ks)*64 + lane)*8);
  }
  // ---- per-lane fused biases
  float cr[2], cz[2], cnh[2], cni[2];
  float wr_[2], wz_[2], wn_[2], mw[2];
  #pragma unroll
  for (int q=0;q<2;++q){
    const int j = (wid*2+q)*16 + l15;
    cr[q]  = bih[j]     + bhh[j];
    cz[q]  = bih[256+j] + bhh[256+j];
    cnh[q] = bhh[512+j];
    cni[q] = bih[512+j];
    if (MODE==0){ wr_[q]=enc_wih[j]; wz_[q]=enc_wih[256+j]; wn_[q]=enc_wih[512+j]; }
    if (MODE==1){ mw[q]=mlin_w[j]; }
  }
  // ---- initial h state -> hbuf[0]
  #pragma unroll
  for (int q=0;q<2;++q){
    const int j = (wid*2+q)*16 + l15;
    #pragma unroll
    for (int r=0;r<4;++r)
      hbuf[hswz(bi0+r, j)] = h_state[(size_t)(b0+bi0+r)*256 + j];
  }
  if (MODE==0){
    if (tid<16){
      const int t = slice*SL;
      xb[tid] = (t==0) ? dpad[b0+tid] : seq[(size_t)(t-1)*BB + b0 + tid];
    }
  } else {
    // ts=0 gi block: 24576 B = 24 chunks of 1 KB; 8 waves x 3 chunks
    #pragma unroll
    for (int k=0;k<3;++k){
      const int c = wid*3 + k;
      gload_lds16((const char*)gi_src + c*1024 + (lane<<4),
                  (char*)gib + c*1024);
    }
  }
  __syncthreads();

  float psum[2][4];
  if (MODE==2){
    #pragma unroll
    for (int q=0;q<2;++q)
      #pragma unroll
      for (int r=0;r<4;++r) psum[q][r]=0.f;
  }

  for (int ts=0; ts<SL; ++ts){
    const int cur = ts & 1;
    f16* hc = hbuf + cur*4096;
    f16* hn = hbuf + (cur^1)*4096;

    // stage next-step inputs into the free LDS half (async; drained by the
    // end-of-step __syncthreads vmcnt(0))
    if (MODE==0){
      if (tid<16 && ts+1<SL){
        const int t = slice*SL + ts + 1;   // >=1 always
        xb[(cur^1)*16 + tid] = seq[(size_t)(t-1)*BB + b0 + tid];
      }
    } else {
      if (ts+1 < SL){
        const char* gsrc = (const char*)gi_src + (size_t)(ts+1)*786432u;
        char* gdst = (char*)gib + (cur^1)*24576;
        #pragma unroll
        for (int k=0;k<3;++k){
          const int c = wid*3 + k;
          gload_lds16(gsrc + c*1024 + (lane<<4), gdst + c*1024);
        }
      }
    }
    // mask output for previous step (reads other buffer of mred; race-free)
    if (MODE==1){
      if (tid<16 && ts>0){
        float v = mlin_b[0];
        #pragma unroll
        for (int w=0;w<8;++w) v += mred[(cur^1)*128 + w*16 + tid];
        out_mask[(size_t)(slice*SL + ts-1)*BB + b0 + tid] = v;
      }
    }

    float mpart[4] = {0.f,0.f,0.f,0.f};
    #pragma unroll
    for (int q=0;q<2;++q){
      const int j = (wid*2+q)*16 + l15;
      f32x4 a0 = {cr[q],cr[q],cr[q],cr[q]};
      f32x4 a1 = {cz[q],cz[q],cz[q],cz[q]};
      f32x4 a2 = {cnh[q],cnh[q],cnh[q],cnh[q]};
      #pragma unroll
      for (int ks=0;ks<8;++ks){
        const f16x8 a = *(const f16x8*)(hc + l15*256 + ((((ks*4+lhi) ^ (l15&7)))<<3));
        a0 = __builtin_amdgcn_mfma_f32_16x16x32_f16(a, wf[q][0][ks], a0, 0,0,0);
        a1 = __builtin_amdgcn_mfma_f32_16x16x32_f16(a, wf[q][1][ks], a1, 0,0,0);
        a2 = __builtin_amdgcn_mfma_f32_16x16x32_f16(a, wf[q][2][ks], a2, 0,0,0);
      }
      float gir[4], giz[4], gin[4];
      if (MODE==0){
        #pragma unroll
        for (int r=0;r<4;++r){
          const float x = xb[cur*16 + bi0 + r];
          gir[r]=x*wr_[q]; giz[r]=x*wz_[q]; gin[r]=x*wn_[q];
        }
      } else {
        const f16* gb = gib + cur*12288;
        const f16x4 g0v = *(const f16x4*)(gb + j*16 + bi0);
        const f16x4 g1v = *(const f16x4*)(gb + (256+j)*16 + bi0);
        const f16x4 g2v = *(const f16x4*)(gb + (512+j)*16 + bi0);
        #pragma unroll
        for (int r=0;r<4;++r){ gir[r]=(float)g0v[r]; giz[r]=(float)g1v[r]; gin[r]=(float)g2v[r]; }
      }
      #pragma unroll
      for (int r=0;r<4;++r){
        const int sz = hswz(bi0+r, j);
        const float hprev = (float)hc[sz];
        const float rr = sigf(gir[r] + a0[r]);
        const float zz = sigf(giz[r] + a1[r]);
        const float nn = tanh_(gin[r] + cni[q] + rr*a2[r]);
        const float h  = (1.f-zz)*nn + zz*hprev;
        hn[sz] = (f16)h;
        if (MODE==0) he_buf[((size_t)ts*BB + (b0+bi0+r))*HH + j] = (f16)h;
        if (MODE==1) mpart[r] += h*mw[q];
        if (MODE==2) psum[q][r] += h;
      }
    }
    if (MODE==1){
      #pragma unroll
      for (int m=1;m<16;m<<=1){
        #pragma unroll
        for (int r=0;r<4;++r) mpart[r] += __shfl_xor(mpart[r], m, 64);
      }
      if (l15==0){
        #pragma unroll
        for (int r=0;r<4;++r) mred[cur*128 + wid*16 + bi0 + r] = mpart[r];
      }
    }
    __syncthreads();
  }

  // final mask row
  if (MODE==1 && tid<16){
    float v = mlin_b[0];
    #pragma unroll
    for (int w=0;w<8;++w) v += mred[((SL-1)&1)*128 + w*16 + tid];
    out_mask[(size_t)(slice*SL + SL-1)*BB + b0 + tid] = v;
  }
  // h state writeback from final buffer
  {
    const f16* hf = hbuf + (SL&1)*4096;
    #pragma unroll
    for (int q=0;q<2;++q){
      const int j = (wid*2+q)*16 + l15;
      #pragma unroll
      for (int r=0;r<4;++r)
        h_state[(size_t)(b0+bi0+r)*256 + j] = hf[hswz(bi0+r, j)];
    }
  }
  if (MODE==2){
    #pragma unroll
    for (int q=0;q<2;++q){
      const int j = (wid*2+q)*16 + l15;
      #pragma unroll
      for (int r=0;r<4;++r){
        const size_t idx = (size_t)(b0+bi0+r)*256 + j;
        hpsum[idx] = hpsum[idx] + psum[q][r];
      }
    }
  }
}

// combined launcher kernel: blocks [0,n_dec) = decoders (16 mdec + 16 pdec),
// blocks [n_dec, n_dec+16) = encoder for slice enc_slice.
__global__ __launch_bounds__(512,2) void rec_kernel(
  const float* __restrict__ seq, const float* __restrict__ dpad,
  const float* __restrict__ enc_wih, const float* __restrict__ enc_bih, const float* __restrict__ enc_bhh,
  const float* __restrict__ mdec_bih, const float* __restrict__ mdec_bhh,
  const float* __restrict__ pdec_bih, const float* __restrict__ pdec_bhh,
  const float* __restrict__ mlin_w, const float* __restrict__ mlin_b,
  const f16* __restrict__ wfrag_enc, const f16* __restrict__ wfrag_m, const f16* __restrict__ wfrag_p,
  f16* __restrict__ he_st, f16* __restrict__ hm_st, f16* __restrict__ hp_st,
  f16* __restrict__ he_buf, const f16* __restrict__ gi_buf,
  float* __restrict__ hpsum, float* __restrict__ out_mask,
  int dec_slice, int enc_slice, int n_dec, int SL)
{
  __shared__ __align__(16) unsigned char smem[16384 + 49152 + 128 + 1024];
  const int bid = blockIdx.x;
  if (bid < n_dec){
    const int rec = bid >> 4, bt = bid & 15;
    const f16* gsrc = gi_buf + ((size_t)bt*1536 + (size_t)rec*768)*16;
    if (rec==0)
      gru_run<1>(bt, dec_slice, SL, wfrag_m, mdec_bih, mdec_bhh, nullptr, nullptr, nullptr,
                 gsrc, hm_st, nullptr, mlin_w, mlin_b, out_mask, nullptr, smem);
    else
      gru_run<2>(bt, dec_slice, SL, wfrag_p, pdec_bih, pdec_bhh, nullptr, nullptr, nullptr,
                 gsrc, hp_st, nullptr, nullptr, nullptr, nullptr, hpsum, smem);
  } else {
    const int bt = bid - n_dec;
    gru_run<0>(bt, enc_slice, SL, wfrag_enc, enc_bih, enc_bhh, enc_wih, seq, dpad,
               nullptr, he_st, he_buf, nullptr, nullptr, nullptr, nullptr, smem);
  }
}

// =====================================================================
// GI: gi[t][b][n] = he[t][b][:] . w_ih_cat[n][:]  (both decoders, n<768 mdec)
// grid = SL*4 blocks (ts, batch-quarter), 256 threads
// =====================================================================
__global__ __launch_bounds__(256,4) void gi_kernel(
  const f16* __restrict__ he_buf, const f16* __restrict__ wfrag_gi,
  f16* __restrict__ gi_buf)
{
  const int ts = blockIdx.x >> 2;
  const int bq = blockIdx.x & 3;
  const int tid = threadIdx.x, lane = tid&63, wid = tid>>6;
  const int l15 = lane&15, lhi = lane>>4;
  __shared__ f16 het[64*264];
  {
    const uint4* src = (const uint4*)(he_buf + ((size_t)ts*BB + bq*64)*HH);
    uint4* dst = (uint4*)het;
    #pragma unroll
    for (int k=0;k<8;++k){
      const int i = tid + k*256;                 // 2048 uint4 = 64 rows x 32
      dst[(i>>5)*33 + (i&31)] = src[i];
    }
  }
  __syncthreads();
  for (int mi=0; mi<24; ++mi){
    const int mt = wid*24 + mi;
    f32x4 acc[4] = {{0,0,0,0},{0,0,0,0},{0,0,0,0},{0,0,0,0}};
    #pragma unroll
    for (int ks=0;ks<8;++ks){
      const f16x8 a = *(const f16x8*)(wfrag_gi + ((size_t)(mt*8+ks)*64 + lane)*8);
      #pragma unroll
      for (int bt=0;bt<4;++bt){
        const f16x8 b = *(const f16x8*)(het + (bt*16+l15)*264 + ks*32 + lhi*8);
        acc[bt] = __builtin_amdgcn_mfma_f32_16x16x32_f16(a, b, acc[bt], 0,0,0);
      }
    }
    #pragma unroll
    for (int bt=0;bt<4;++bt){
      const int btg = bq*4 + bt;
      const size_t base = (((size_t)ts*16 + btg)*1536 + (size_t)mt*16 + lhi*4)*16 + l15;
      #pragma unroll
      for (int r=0;r<4;++r) gi_buf[base + (size_t)r*16] = (f16)acc[bt][r];
    }
  }
}

// =====================================================================
// PRED: pred[b][p] = (hpsum[b]/512) . plin_w[p] + plin_b[p]
// =====================================================================
__global__ __launch_bounds__(256,1) void pred_kernel(
  const float* __restrict__ hpsum, const float* __restrict__ plin_w,
  const float* __restrict__ plin_b, float* __restrict__ out)
{
  __shared__ float hs[256];
  const int p = threadIdx.x;
  const float bias = plin_b[p];
  for (int bb=0; bb<4; ++bb){
    const int b = blockIdx.x*4 + bb;
    __syncthreads();
    hs[p] = hpsum[(size_t)b*256 + p];
    __syncthreads();
    float acc = 0.f;
    const float4* wrow = (const float4*)(plin_w + (size_t)p*256);
    #pragma unroll 4
    for (int k4=0;k4<64;++k4){
      const float4 w = wrow[k4];
      acc += hs[k4*4+0]*w.x + hs[k4*4+1]*w.y + hs[k4*4+2]*w.z + hs[k4*4+3]*w.w;
    }
    out[131072 + (size_t)b*256 + p] = acc*(1.f/512.f) + bias;
  }
}

// =====================================================================
extern "C" void kernel_launch(void* const* d_in, const int* in_sizes, int n_in,
                              void* d_out, int out_size, void* d_ws, size_t ws_size,
                              hipStream_t stream)
{
  const float* seq      = (const float*)d_in[0];
  const float* dpad     = (const float*)d_in[1];
  const float* h0e      = (const float*)d_in[2];
  const float* h0m      = (const float*)d_in[3];
  const float* h0p      = (const float*)d_in[4];
  const float* enc_wih  = (const float*)d_in[5];
  const float* enc_whh  = (const float*)d_in[6];
  const float* enc_bih  = (const float*)d_in[7];
  const float* enc_bhh  = (const float*)d_in[8];
  const float* mdec_wih = (const float*)d_in[9];
  const float* mdec_whh = (const float*)d_in[10];
  const float* mdec_bih = (const float*)d_in[11];
  const float* mdec_bhh = (const float*)d_in[12];
  const float* mlin_w   = (const float*)d_in[13];
  const float* mlin_b   = (const float*)d_in[14];
  const float* pdec_wih = (const float*)d_in[15];
  const float* pdec_whh = (const float*)d_in[16];
  const float* pdec_bih = (const float*)d_in[17];
  const float* pdec_bhh = (const float*)d_in[18];
  const float* plin_w   = (const float*)d_in[19];
  const float* plin_b   = (const float*)d_in[20];
  float* out = (float*)d_out;

  char* ws = (char*)d_ws;
  f16* wfrag_enc = (f16*)(ws + O_WFRAG_ENC);
  f16* wfrag_m   = (f16*)(ws + O_WFRAG_M);
  f16* wfrag_p   = (f16*)(ws + O_WFRAG_P);
  f16* wfrag_gi  = (f16*)(ws + O_WFRAG_GI);
  f16* he_st     = (f16*)(ws + O_HE_ST);
  f16* hm_st     = (f16*)(ws + O_HM_ST);
  f16* hp_st     = (f16*)(ws + O_HP_ST);
  float* hpsum   = (float*)(ws + O_HPSUM);

  int SL = 64;  // time-slice length; shrink to fit workspace
  while (SL > 1 && (size_t)O_DYN + (size_t)SL*DYN_PER_STEP > ws_size) SL >>= 1;
  const int S = TT / SL;
  f16* he_buf = (f16*)(ws + O_DYN);
  f16* gi_buf = (f16*)(ws + O_DYN + (size_t)SL*131072u);

  prep_kernel<<<dim3(4096), dim3(256), 0, stream>>>(
      enc_whh, mdec_whh, pdec_whh, mdec_wih, pdec_wih, h0e, h0m, h0p,
      wfrag_enc, wfrag_m, wfrag_p, wfrag_gi, he_st, hm_st, hp_st, hpsum);

  // encoder slice 0 (no decoders yet)
  rec_kernel<<<dim3(16), dim3(512), 0, stream>>>(
      seq, dpad, enc_wih, enc_bih, enc_bhh, mdec_bih, mdec_bhh, pdec_bih, pdec_bhh,
      mlin_w, mlin_b, wfrag_enc, wfrag_m, wfrag_p, he_st, hm_st, hp_st,
      he_buf, gi_buf, hpsum, out, 0, 0, 0, SL);
  gi_kernel<<<dim3(SL*4), dim3(256), 0, stream>>>(he_buf, wfrag_gi, gi_buf);

  for (int s=0; s<S; ++s){
    const int has_enc = (s+1 < S);
    rec_kernel<<<dim3(has_enc?48:32), dim3(512), 0, stream>>>(
        seq, dpad, enc_wih, enc_bih, enc_bhh, mdec_bih, mdec_bhh, pdec_bih, pdec_bhh,
        mlin_w, mlin_b, wfrag_enc, wfrag_m, wfrag_p, he_st, hm_st, hp_st,
        he_buf, gi_buf, hpsum, out, s, s+1, 32, SL);
    if (has_enc)
      gi_kernel<<<dim3(SL*4), dim3(256), 0, stream>>>(he_buf, wfrag_gi, gi_buf);
  }

  pred_kernel<<<dim3(64), dim3(256), 0, stream>>>(hpsum, plin_w, plin_b, out);
}

// Round 3
// 3436.412 us; speedup vs baseline: 1.2414x; 1.0247x over previous
//
#include <hip/hip_runtime.h>
#include <hip/hip_fp16.h>

typedef _Float16 f16;
typedef _Float16 f16x8 __attribute__((ext_vector_type(8)));
typedef _Float16 f16x4 __attribute__((ext_vector_type(4)));
typedef float    f32x4 __attribute__((ext_vector_type(4)));

#define TT 512
#define BB 256
#define HH 256

// ---- workspace byte offsets (fixed region) ----
#define O_WFRAG_ENC 0u
#define O_WFRAG_M   393216u
#define O_WFRAG_P   786432u
#define O_WFRAG_GI  1179648u
#define O_HE_ST     1966080u
#define O_HM_ST     2097152u
#define O_HP_ST     2228224u
#define O_HPSUM     2359296u
#define O_DYN       2621440u
// per-slice-step dynamic bytes: he_buf 131072 + gi_buf 786432
#define DYN_PER_STEP 917504u

__device__ __forceinline__ float sigf(float x){ return 1.0f/(1.0f+__expf(-x)); }
__device__ __forceinline__ float tanh_(float x){
  float xc = fminf(fmaxf(x,-15.f),15.f);
  float e  = __expf(2.f*xc);
  return (e-1.f)/(e+1.f);
}
// XOR-swizzled element index into a [16][256] f16 tile (16B granules ^ row&7)
__device__ __forceinline__ int hswz(int row, int j){
  return row*256 + ((((j>>3) ^ (row&7)))<<3) + (j&7);
}
// async global->LDS, 16B per lane (dest = wave-uniform base + lane*16)
__device__ __forceinline__ void gload_lds16(const void* g, void* l){
  __builtin_amdgcn_global_load_lds(
      (const __attribute__((address_space(1))) unsigned int*)g,
      (__attribute__((address_space(3))) unsigned int*)l, 16, 0, 0);
}

// =====================================================================
// PREP: convert f32 weights -> f16 fragment-ordered buffers, init states
// =====================================================================
__global__ void prep_kernel(
    const float* __restrict__ enc_whh, const float* __restrict__ mdec_whh,
    const float* __restrict__ pdec_whh, const float* __restrict__ mdec_wih,
    const float* __restrict__ pdec_wih,
    const float* __restrict__ h0e, const float* __restrict__ h0m, const float* __restrict__ h0p,
    f16* __restrict__ wfrag_enc, f16* __restrict__ wfrag_m, f16* __restrict__ wfrag_p,
    f16* __restrict__ wfrag_gi,
    f16* __restrict__ he_st, f16* __restrict__ hm_st, f16* __restrict__ hp_st,
    float* __restrict__ hpsum)
{
  int idx = blockIdx.x*256 + threadIdx.x;
  const int NW = 16*3*8*64*8; // 196608 per recurrence buffer
  if (idx < 3*NW){
    int b = idx / NW, e = idx % NW;
    int jj = e & 7, l = (e>>3)&63, ks = (e>>9)&7, t2 = e>>12;
    int g = t2 % 3, w = t2 / 3;                 // w = j-block 0..15
    int row = g*256 + w*16 + (l&15);            // gate row of W_hh
    int col = ks*32 + (l>>4)*8 + jj;            // k index
    const float* W = (b==0)?enc_whh:((b==1)?mdec_whh:pdec_whh);
    f16* D = (b==0)?wfrag_enc:((b==1)?wfrag_m:wfrag_p);
    D[e] = (f16)W[row*256+col];
    return;
  }
  idx -= 3*NW;
  const int NG = 96*8*64*8; // 393216 : concat [mdec_wih; pdec_wih] fragments
  if (idx < NG){
    int e = idx;
    int jj = e&7, l=(e>>3)&63, ks=(e>>9)&7, mt = e>>12; // mt 0..95
    int row = mt*16 + (l&15);                   // 0..1535
    int col = ks*32 + (l>>4)*8 + jj;
    float v = (row < 768) ? mdec_wih[row*256+col] : pdec_wih[(row-768)*256+col];
    wfrag_gi[e] = (f16)v;
    return;
  }
  idx -= NG;
  if (idx < 65536){
    he_st[idx] = (f16)h0e[idx];
    hm_st[idx] = (f16)h0m[idx];
    hp_st[idx] = (f16)h0p[idx];
    hpsum[idx] = 0.f;
  }
}

// =====================================================================
// Recurrence core. MODE 0=encoder, 1=mask-decoder, 2=pred-decoder.
// 512 threads (8 waves) per 16-row batch tile. Each wave owns a 32-wide
// j-slice: wf[2][3][8] = 192 VGPRs of W_hh fragments, PINNED in registers
// via asm so the compiler cannot spill/sink the loads into the loop.
// h in LDS (swizzled, double-buffered). Decoder gi staged via
// global_load_lds into the free half of the LDS double buffer (0 VGPRs).
// =====================================================================
template<int MODE>
__device__ __forceinline__ void gru_run(
  int bt, int slice, int SL,
  const f16* __restrict__ wfrag,
  const float* __restrict__ bih, const float* __restrict__ bhh,
  const float* __restrict__ enc_wih,
  const float* __restrict__ seq, const float* __restrict__ dpad,
  const f16* __restrict__ gi_src,      // pre-offset for (bt, rec)
  f16* __restrict__ h_state,
  f16* __restrict__ he_buf,
  const float* __restrict__ mlin_w, const float* __restrict__ mlin_b,
  float* __restrict__ out_mask,
  float* __restrict__ hpsum,
  unsigned char* smem)
{
  const int tid = threadIdx.x;       // 512
  const int lane = tid & 63;
  const int wid  = tid >> 6;         // 0..7
  const int l15  = lane & 15;
  const int lhi  = lane >> 4;        // 0..3
  const int bi0  = lhi*4;
  const int b0   = bt*16;

  f16* hbuf  = (f16*)smem;                        // [2][16*256] swizzled (16 KB)
  f16* gib   = (f16*)(smem + 16384);              // [2][12288]        (48 KB)
  float* xb  = (float*)(smem + 16384 + 49152);    // [2][16]
  float* mred = xb + 32;                          // [2][8 waves][16 rows]

  // ---- resident B-fragments: wf[q][gate][kstep], j-block = wid*2+q
  f32x4 wf[2][3][8];
  #pragma unroll
  for (int q=0;q<2;++q){
    const int w = wid*2+q;
    #pragma unroll
    for (int g=0;g<3;++g)
      #pragma unroll
      for (int ks=0;ks<8;++ks)
        wf[q][g][ks] = *(const f32x4*)(wfrag + ((size_t)(((w*3+g)*8)+ks)*64 + lane)*8);
  }
  // pin: forces true register residency across the ts-loop
  #pragma unroll
  for (int q=0;q<2;++q)
    #pragma unroll
    for (int g=0;g<3;++g)
      #pragma unroll
      for (int ks=0;ks<8;++ks)
        asm volatile("" : "+v"(wf[q][g][ks]));

  // ---- per-lane fused biases
  float cr[2], cz[2], cnh[2], cni[2];
  float wr_[2], wz_[2], wn_[2], mw[2];
  #pragma unroll
  for (int q=0;q<2;++q){
    const int j = (wid*2+q)*16 + l15;
    cr[q]  = bih[j]     + bhh[j];
    cz[q]  = bih[256+j] + bhh[256+j];
    cnh[q] = bhh[512+j];
    cni[q] = bih[512+j];
    if (MODE==0){ wr_[q]=enc_wih[j]; wz_[q]=enc_wih[256+j]; wn_[q]=enc_wih[512+j]; }
    if (MODE==1){ mw[q]=mlin_w[j]; }
  }
  // ---- initial h state -> hbuf[0]
  #pragma unroll
  for (int q=0;q<2;++q){
    const int j = (wid*2+q)*16 + l15;
    #pragma unroll
    for (int r=0;r<4;++r)
      hbuf[hswz(bi0+r, j)] = h_state[(size_t)(b0+bi0+r)*256 + j];
  }
  if (MODE==0){
    if (tid<16){
      const int t = slice*SL;
      xb[tid] = (t==0) ? dpad[b0+tid] : seq[(size_t)(t-1)*BB + b0 + tid];
    }
  } else {
    // ts=0 gi block: 24576 B = 24 chunks of 1 KB; 8 waves x 3 chunks
    #pragma unroll
    for (int k=0;k<3;++k){
      const int c = wid*3 + k;
      gload_lds16((const char*)gi_src + c*1024 + (lane<<4),
                  (char*)gib + c*1024);
    }
  }
  __syncthreads();

  float psum[2][4];
  if (MODE==2){
    #pragma unroll
    for (int q=0;q<2;++q)
      #pragma unroll
      for (int r=0;r<4;++r) psum[q][r]=0.f;
  }

  for (int ts=0; ts<SL; ++ts){
    const int cur = ts & 1;
    f16* hc = hbuf + cur*4096;
    f16* hn = hbuf + (cur^1)*4096;

    // stage next-step inputs into the free LDS half (async; drained by the
    // end-of-step __syncthreads vmcnt(0))
    if (MODE==0){
      if (tid<16 && ts+1<SL){
        const int t = slice*SL + ts + 1;   // >=1 always
        xb[(cur^1)*16 + tid] = seq[(size_t)(t-1)*BB + b0 + tid];
      }
    } else {
      if (ts+1 < SL){
        const char* gsrc = (const char*)gi_src + (size_t)(ts+1)*786432u;
        char* gdst = (char*)gib + (cur^1)*24576;
        #pragma unroll
        for (int k=0;k<3;++k){
          const int c = wid*3 + k;
          gload_lds16(gsrc + c*1024 + (lane<<4), gdst + c*1024);
        }
      }
    }
    // mask output for previous step (reads other buffer of mred; race-free)
    if (MODE==1){
      if (tid<16 && ts>0){
        float v = mlin_b[0];
        #pragma unroll
        for (int w=0;w<8;++w) v += mred[(cur^1)*128 + w*16 + tid];
        out_mask[(size_t)(slice*SL + ts-1)*BB + b0 + tid] = v;
      }
    }

    float mpart[4] = {0.f,0.f,0.f,0.f};
    #pragma unroll
    for (int q=0;q<2;++q){
      const int j = (wid*2+q)*16 + l15;
      f32x4 a0 = {cr[q],cr[q],cr[q],cr[q]};
      f32x4 a1 = {cz[q],cz[q],cz[q],cz[q]};
      f32x4 a2 = {cnh[q],cnh[q],cnh[q],cnh[q]};
      #pragma unroll
      for (int ks=0;ks<8;++ks){
        const f16x8 a = *(const f16x8*)(hc + l15*256 + ((((ks*4+lhi) ^ (l15&7)))<<3));
        a0 = __builtin_amdgcn_mfma_f32_16x16x32_f16(a, __builtin_bit_cast(f16x8, wf[q][0][ks]), a0, 0,0,0);
        a1 = __builtin_amdgcn_mfma_f32_16x16x32_f16(a, __builtin_bit_cast(f16x8, wf[q][1][ks]), a1, 0,0,0);
        a2 = __builtin_amdgcn_mfma_f32_16x16x32_f16(a, __builtin_bit_cast(f16x8, wf[q][2][ks]), a2, 0,0,0);
      }
      float gir[4], giz[4], gin[4];
      if (MODE==0){
        #pragma unroll
        for (int r=0;r<4;++r){
          const float x = xb[cur*16 + bi0 + r];
          gir[r]=x*wr_[q]; giz[r]=x*wz_[q]; gin[r]=x*wn_[q];
        }
      } else {
        const f16* gb = gib + cur*12288;
        const f16x4 g0v = *(const f16x4*)(gb + j*16 + bi0);
        const f16x4 g1v = *(const f16x4*)(gb + (256+j)*16 + bi0);
        const f16x4 g2v = *(const f16x4*)(gb + (512+j)*16 + bi0);
        #pragma unroll
        for (int r=0;r<4;++r){ gir[r]=(float)g0v[r]; giz[r]=(float)g1v[r]; gin[r]=(float)g2v[r]; }
      }
      #pragma unroll
      for (int r=0;r<4;++r){
        const int sz = hswz(bi0+r, j);
        const float hprev = (float)hc[sz];
        const float rr = sigf(gir[r] + a0[r]);
        const float zz = sigf(giz[r] + a1[r]);
        const float nn = tanh_(gin[r] + cni[q] + rr*a2[r]);
        const float h  = (1.f-zz)*nn + zz*hprev;
        hn[sz] = (f16)h;
        if (MODE==0) he_buf[((size_t)ts*BB + (b0+bi0+r))*HH + j] = (f16)h;
        if (MODE==1) mpart[r] += h*mw[q];
        if (MODE==2) psum[q][r] += h;
      }
    }
    if (MODE==1){
      #pragma unroll
      for (int m=1;m<16;m<<=1){
        #pragma unroll
        for (int r=0;r<4;++r) mpart[r] += __shfl_xor(mpart[r], m, 64);
      }
      if (l15==0){
        #pragma unroll
        for (int r=0;r<4;++r) mred[cur*128 + wid*16 + bi0 + r] = mpart[r];
      }
    }
    __syncthreads();
  }

  // final mask row
  if (MODE==1 && tid<16){
    float v = mlin_b[0];
    #pragma unroll
    for (int w=0;w<8;++w) v += mred[((SL-1)&1)*128 + w*16 + tid];
    out_mask[(size_t)(slice*SL + SL-1)*BB + b0 + tid] = v;
  }
  // h state writeback from final buffer
  {
    const f16* hf = hbuf + (SL&1)*4096;
    #pragma unroll
    for (int q=0;q<2;++q){
      const int j = (wid*2+q)*16 + l15;
      #pragma unroll
      for (int r=0;r<4;++r)
        h_state[(size_t)(b0+bi0+r)*256 + j] = hf[hswz(bi0+r, j)];
    }
  }
  if (MODE==2){
    #pragma unroll
    for (int q=0;q<2;++q){
      const int j = (wid*2+q)*16 + l15;
      #pragma unroll
      for (int r=0;r<4;++r){
        const size_t idx = (size_t)(b0+bi0+r)*256 + j;
        hpsum[idx] = hpsum[idx] + psum[q][r];
      }
    }
  }
}

// combined launcher kernel: blocks [0,n_dec) = decoders (16 mdec + 16 pdec),
// blocks [n_dec, n_dec+16) = encoder for slice enc_slice.
__global__ __launch_bounds__(512,2) void rec_kernel(
  const float* __restrict__ seq, const float* __restrict__ dpad,
  const float* __restrict__ enc_wih, const float* __restrict__ enc_bih, const float* __restrict__ enc_bhh,
  const float* __restrict__ mdec_bih, const float* __restrict__ mdec_bhh,
  const float* __restrict__ pdec_bih, const float* __restrict__ pdec_bhh,
  const float* __restrict__ mlin_w, const float* __restrict__ mlin_b,
  const f16* __restrict__ wfrag_enc, const f16* __restrict__ wfrag_m, const f16* __restrict__ wfrag_p,
  f16* __restrict__ he_st, f16* __restrict__ hm_st, f16* __restrict__ hp_st,
  f16* __restrict__ he_buf, const f16* __restrict__ gi_buf,
  float* __restrict__ hpsum, float* __restrict__ out_mask,
  int dec_slice, int enc_slice, int n_dec, int SL)
{
  __shared__ __align__(16) unsigned char smem[16384 + 49152 + 128 + 1024];
  const int bid = blockIdx.x;
  if (bid < n_dec){
    const int rec = bid >> 4, bt = bid & 15;
    const f16* gsrc = gi_buf + ((size_t)bt*1536 + (size_t)rec*768)*16;
    if (rec==0)
      gru_run<1>(bt, dec_slice, SL, wfrag_m, mdec_bih, mdec_bhh, nullptr, nullptr, nullptr,
                 gsrc, hm_st, nullptr, mlin_w, mlin_b, out_mask, nullptr, smem);
    else
      gru_run<2>(bt, dec_slice, SL, wfrag_p, pdec_bih, pdec_bhh, nullptr, nullptr, nullptr,
                 gsrc, hp_st, nullptr, nullptr, nullptr, nullptr, hpsum, smem);
  } else {
    const int bt = bid - n_dec;
    gru_run<0>(bt, enc_slice, SL, wfrag_enc, enc_bih, enc_bhh, enc_wih, seq, dpad,
               nullptr, he_st, he_buf, nullptr, nullptr, nullptr, nullptr, smem);
  }
}

// =====================================================================
// GI: gi[t][b][n] = he[t][b][:] . w_ih_cat[n][:]  (both decoders, n<768 mdec)
// grid = SL*4 blocks (ts, batch-quarter), 256 threads
// =====================================================================
__global__ __launch_bounds__(256,4) void gi_kernel(
  const f16* __restrict__ he_buf, const f16* __restrict__ wfrag_gi,
  f16* __restrict__ gi_buf)
{
  const int ts = blockIdx.x >> 2;
  const int bq = blockIdx.x & 3;
  const int tid = threadIdx.x, lane = tid&63, wid = tid>>6;
  const int l15 = lane&15, lhi = lane>>4;
  __shared__ f16 het[64*264];
  {
    const uint4* src = (const uint4*)(he_buf + ((size_t)ts*BB + bq*64)*HH);
    uint4* dst = (uint4*)het;
    #pragma unroll
    for (int k=0;k<8;++k){
      const int i = tid + k*256;                 // 2048 uint4 = 64 rows x 32
      dst[(i>>5)*33 + (i&31)] = src[i];
    }
  }
  __syncthreads();
  for (int mi=0; mi<24; ++mi){
    const int mt = wid*24 + mi;
    f32x4 acc[4] = {{0,0,0,0},{0,0,0,0},{0,0,0,0},{0,0,0,0}};
    #pragma unroll
    for (int ks=0;ks<8;++ks){
      const f16x8 a = *(const f16x8*)(wfrag_gi + ((size_t)(mt*8+ks)*64 + lane)*8);
      #pragma unroll
      for (int bt=0;bt<4;++bt){
        const f16x8 b = *(const f16x8*)(het + (bt*16+l15)*264 + ks*32 + lhi*8);
        acc[bt] = __builtin_amdgcn_mfma_f32_16x16x32_f16(a, b, acc[bt], 0,0,0);
      }
    }
    #pragma unroll
    for (int bt=0;bt<4;++bt){
      const int btg = bq*4 + bt;
      const size_t base = (((size_t)ts*16 + btg)*1536 + (size_t)mt*16 + lhi*4)*16 + l15;
      #pragma unroll
      for (int r=0;r<4;++r) gi_buf[base + (size_t)r*16] = (f16)acc[bt][r];
    }
  }
}

// =====================================================================
// PRED: pred[b][p] = (hpsum[b]/512) . plin_w[p] + plin_b[p]
// =====================================================================
__global__ __launch_bounds__(256,1) void pred_kernel(
  const float* __restrict__ hpsum, const float* __restrict__ plin_w,
  const float* __restrict__ plin_b, float* __restrict__ out)
{
  __shared__ float hs[256];
  const int p = threadIdx.x;
  const float bias = plin_b[p];
  for (int bb=0; bb<4; ++bb){
    const int b = blockIdx.x*4 + bb;
    __syncthreads();
    hs[p] = hpsum[(size_t)b*256 + p];
    __syncthreads();
    float acc = 0.f;
    const float4* wrow = (const float4*)(plin_w + (size_t)p*256);
    #pragma unroll 4
    for (int k4=0;k4<64;++k4){
      const float4 w = wrow[k4];
      acc += hs[k4*4+0]*w.x + hs[k4*4+1]*w.y + hs[k4*4+2]*w.z + hs[k4*4+3]*w.w;
    }
    out[131072 + (size_t)b*256 + p] = acc*(1.f/512.f) + bias;
  }
}

// =====================================================================
extern "C" void kernel_launch(void* const* d_in, const int* in_sizes, int n_in,
                              void* d_out, int out_size, void* d_ws, size_t ws_size,
                              hipStream_t stream)
{
  const float* seq      = (const float*)d_in[0];
  const float* dpad     = (const float*)d_in[1];
  const float* h0e      = (const float*)d_in[2];
  const float* h0m      = (const float*)d_in[3];
  const float* h0p      = (const float*)d_in[4];
  const float* enc_wih  = (const float*)d_in[5];
  const float* enc_whh  = (const float*)d_in[6];
  const float* enc_bih  = (const float*)d_in[7];
  const float* enc_bhh  = (const float*)d_in[8];
  const float* mdec_wih = (const float*)d_in[9];
  const float* mdec_whh = (const float*)d_in[10];
  const float* mdec_bih = (const float*)d_in[11];
  const float* mdec_bhh = (const float*)d_in[12];
  const float* mlin_w   = (const float*)d_in[13];
  const float* mlin_b   = (const float*)d_in[14];
  const float* pdec_wih = (const float*)d_in[15];
  const float* pdec_whh = (const float*)d_in[16];
  const float* pdec_bih = (const float*)d_in[17];
  const float* pdec_bhh = (const float*)d_in[18];
  const float* plin_w   = (const float*)d_in[19];
  const float* plin_b   = (const float*)d_in[20];
  float* out = (float*)d_out;

  char* ws = (char*)d_ws;
  f16* wfrag_enc = (f16*)(ws + O_WFRAG_ENC);
  f16* wfrag_m   = (f16*)(ws + O_WFRAG_M);
  f16* wfrag_p   = (f16*)(ws + O_WFRAG_P);
  f16* wfrag_gi  = (f16*)(ws + O_WFRAG_GI);
  f16* he_st     = (f16*)(ws + O_HE_ST);
  f16* hm_st     = (f16*)(ws + O_HM_ST);
  f16* hp_st     = (f16*)(ws + O_HP_ST);
  float* hpsum   = (float*)(ws + O_HPSUM);

  int SL = 64;  // time-slice length; shrink to fit workspace
  while (SL > 1 && (size_t)O_DYN + (size_t)SL*DYN_PER_STEP > ws_size) SL >>= 1;
  const int S = TT / SL;
  f16* he_buf = (f16*)(ws + O_DYN);
  f16* gi_buf = (f16*)(ws + O_DYN + (size_t)SL*131072u);

  prep_kernel<<<dim3(4096), dim3(256), 0, stream>>>(
      enc_whh, mdec_whh, pdec_whh, mdec_wih, pdec_wih, h0e, h0m, h0p,
      wfrag_enc, wfrag_m, wfrag_p, wfrag_gi, he_st, hm_st, hp_st, hpsum);

  // encoder slice 0 (no decoders yet)
  rec_kernel<<<dim3(16), dim3(512), 0, stream>>>(
      seq, dpad, enc_wih, enc_bih, enc_bhh, mdec_bih, mdec_bhh, pdec_bih, pdec_bhh,
      mlin_w, mlin_b, wfrag_enc, wfrag_m, wfrag_p, he_st, hm_st, hp_st,
      he_buf, gi_buf, hpsum, out, 0, 0, 0, SL);
  gi_kernel<<<dim3(SL*4), dim3(256), 0, stream>>>(he_buf, wfrag_gi, gi_buf);

  for (int s=0; s<S; ++s){
    const int has_enc = (s+1 < S);
    rec_kernel<<<dim3(has_enc?48:32), dim3(512), 0, stream>>>(
        seq, dpad, enc_wih, enc_bih, enc_bhh, mdec_bih, mdec_bhh, pdec_bih, pdec_bhh,
        mlin_w, mlin_b, wfrag_enc, wfrag_m, wfrag_p, he_st, hm_st, hp_st,
        he_buf, gi_buf, hpsum, out, s, s+1, 32, SL);
    if (has_enc)
      gi_kernel<<<dim3(SL*4), dim3(256), 0, stream>>>(he_buf, wfrag_gi, gi_buf);
  }

  pred_kernel<<<dim3(64), dim3(256), 0, stream>>>(hpsum, plin_w, plin_b, out);
}

// Round 4
// 3348.611 us; speedup vs baseline: 1.2739x; 1.0262x over previous
//
#include <hip/hip_runtime.h>
#include <hip/hip_fp16.h>

typedef _Float16 f16;
typedef _Float16 f16x8 __attribute__((ext_vector_type(8)));
typedef _Float16 f16x4 __attribute__((ext_vector_type(4)));
typedef float    f32x4 __attribute__((ext_vector_type(4)));

#define TT 512
#define BB 256
#define HH 256

// ---- workspace byte offsets (fixed region) ----
#define O_WFRAG_ENC 0u
#define O_WFRAG_M   393216u
#define O_WFRAG_P   786432u
#define O_WFRAG_GI  1179648u
#define O_HE_ST     1966080u
#define O_HM_ST     2097152u
#define O_HP_ST     2228224u
#define O_HPSUM     2359296u
#define O_DYN       2621440u
// per-slice-step dynamic bytes: he_buf 131072 + gi_buf 786432
#define DYN_PER_STEP 917504u

__device__ __forceinline__ float sigf(float x){ return 1.0f/(1.0f+__expf(-x)); }
__device__ __forceinline__ float tanh_(float x){
  float xc = fminf(fmaxf(x,-15.f),15.f);
  float e  = __expf(2.f*xc);
  return (e-1.f)/(e+1.f);
}
// XOR-swizzled element index into a [16][256] f16 tile (16B granules ^ row&7)
__device__ __forceinline__ int hswz(int row, int j){
  return row*256 + ((((j>>3) ^ (row&7)))<<3) + (j&7);
}
// async global->LDS, 16B per lane (dest = wave-uniform base + lane*16)
__device__ __forceinline__ void gload_lds16(const void* g, void* l){
  __builtin_amdgcn_global_load_lds(
      (const __attribute__((address_space(1))) unsigned int*)g,
      (__attribute__((address_space(3))) unsigned int*)l, 16, 0, 0);
}

// =====================================================================
// PREP: convert f32 weights -> f16 fragment-ordered buffers, init states
// =====================================================================
__global__ void prep_kernel(
    const float* __restrict__ enc_whh, const float* __restrict__ mdec_whh,
    const float* __restrict__ pdec_whh, const float* __restrict__ mdec_wih,
    const float* __restrict__ pdec_wih,
    const float* __restrict__ h0e, const float* __restrict__ h0m, const float* __restrict__ h0p,
    f16* __restrict__ wfrag_enc, f16* __restrict__ wfrag_m, f16* __restrict__ wfrag_p,
    f16* __restrict__ wfrag_gi,
    f16* __restrict__ he_st, f16* __restrict__ hm_st, f16* __restrict__ hp_st,
    float* __restrict__ hpsum)
{
  int idx = blockIdx.x*256 + threadIdx.x;
  const int NW = 16*3*8*64*8; // 196608 per recurrence buffer
  if (idx < 3*NW){
    int b = idx / NW, e = idx % NW;
    int jj = e & 7, l = (e>>3)&63, ks = (e>>9)&7, t2 = e>>12;
    int g = t2 % 3, w = t2 / 3;                 // w = j-block 0..15
    int row = g*256 + w*16 + (l&15);            // gate row of W_hh
    int col = ks*32 + (l>>4)*8 + jj;            // k index
    const float* W = (b==0)?enc_whh:((b==1)?mdec_whh:pdec_whh);
    f16* D = (b==0)?wfrag_enc:((b==1)?wfrag_m:wfrag_p);
    D[e] = (f16)W[row*256+col];
    return;
  }
  idx -= 3*NW;
  const int NG = 96*8*64*8; // 393216 : concat [mdec_wih; pdec_wih] fragments
  if (idx < NG){
    int e = idx;
    int jj = e&7, l=(e>>3)&63, ks=(e>>9)&7, mt = e>>12; // mt 0..95
    int row = mt*16 + (l&15);                   // 0..1535
    int col = ks*32 + (l>>4)*8 + jj;
    float v = (row < 768) ? mdec_wih[row*256+col] : pdec_wih[(row-768)*256+col];
    wfrag_gi[e] = (f16)v;
    return;
  }
  idx -= NG;
  if (idx < 65536){
    he_st[idx] = (f16)h0e[idx];
    hm_st[idx] = (f16)h0m[idx];
    hp_st[idx] = (f16)h0p[idx];
    hpsum[idx] = 0.f;
  }
}

// =====================================================================
// Recurrence core. MODE 0=encoder, 1=mask-decoder, 2=pred-decoder.
// 512 threads (8 waves) per 16-row batch tile. Each wave owns a 32-wide
// j-slice: wf[2][3][8] = 192 VGPRs of W_hh fragments. The WG owns the
// ENTIRE CU register file (amdgpu_waves_per_eu(2,2) -> 256 VGPR/wave).
// h in LDS (swizzled, double-buffered). Decoder gi staged via
// global_load_lds into the free half of the LDS double buffer (0 VGPRs).
// =====================================================================
template<int MODE>
__device__ __forceinline__ void gru_run(
  int bt, int slice, int SL,
  const f16* __restrict__ wfrag,
  const float* __restrict__ bih, const float* __restrict__ bhh,
  const float* __restrict__ enc_wih,
  const float* __restrict__ seq, const float* __restrict__ dpad,
  const f16* __restrict__ gi_src,      // pre-offset for (bt, rec)
  f16* __restrict__ h_state,
  f16* __restrict__ he_buf,
  const float* __restrict__ mlin_w, const float* __restrict__ mlin_b,
  float* __restrict__ out_mask,
  float* __restrict__ hpsum,
  unsigned char* smem)
{
  const int tid = threadIdx.x;       // 512
  const int lane = tid & 63;
  const int wid  = tid >> 6;         // 0..7
  const int l15  = lane & 15;
  const int lhi  = lane >> 4;        // 0..3
  const int bi0  = lhi*4;
  const int b0   = bt*16;

  f16* hbuf  = (f16*)smem;                        // [2][16*256] swizzled (16 KB)
  f16* gib   = (f16*)(smem + 16384);              // [2][12288]        (48 KB)
  float* xb  = (float*)(smem + 16384 + 49152);    // [2][16]
  float* mred = xb + 32;                          // [2][8 waves][16 rows]

  // ---- resident B-fragments: wf[q][gate][kstep], j-block = wid*2+q
  f32x4 wf[2][3][8];
  #pragma unroll
  for (int q=0;q<2;++q){
    const int w = wid*2+q;
    #pragma unroll
    for (int g=0;g<3;++g)
      #pragma unroll
      for (int ks=0;ks<8;++ks)
        wf[q][g][ks] = *(const f32x4*)(wfrag + ((size_t)(((w*3+g)*8)+ks)*64 + lane)*8);
  }
  // pin: materialize all fragments before the loop
  #pragma unroll
  for (int q=0;q<2;++q)
    #pragma unroll
    for (int g=0;g<3;++g)
      #pragma unroll
      for (int ks=0;ks<8;++ks)
        asm volatile("" : "+v"(wf[q][g][ks]));

  // ---- per-lane fused biases
  float cr[2], cz[2], cnh[2], cni[2];
  float wr_[2], wz_[2], wn_[2], mw[2];
  #pragma unroll
  for (int q=0;q<2;++q){
    const int j = (wid*2+q)*16 + l15;
    cr[q]  = bih[j]     + bhh[j];
    cz[q]  = bih[256+j] + bhh[256+j];
    cnh[q] = bhh[512+j];
    cni[q] = bih[512+j];
    if (MODE==0){ wr_[q]=enc_wih[j]; wz_[q]=enc_wih[256+j]; wn_[q]=enc_wih[512+j]; }
    if (MODE==1){ mw[q]=mlin_w[j]; }
  }
  // ---- initial h state -> hbuf[0]
  #pragma unroll
  for (int q=0;q<2;++q){
    const int j = (wid*2+q)*16 + l15;
    #pragma unroll
    for (int r=0;r<4;++r)
      hbuf[hswz(bi0+r, j)] = h_state[(size_t)(b0+bi0+r)*256 + j];
  }
  if (MODE==0){
    if (tid<16){
      const int t = slice*SL;
      xb[tid] = (t==0) ? dpad[b0+tid] : seq[(size_t)(t-1)*BB + b0 + tid];
    }
  } else {
    // ts=0 gi block: 24576 B = 24 chunks of 1 KB; 8 waves x 3 chunks
    #pragma unroll
    for (int k=0;k<3;++k){
      const int c = wid*3 + k;
      gload_lds16((const char*)gi_src + c*1024 + (lane<<4),
                  (char*)gib + c*1024);
    }
  }
  __syncthreads();

  float psum[2][4];
  if (MODE==2){
    #pragma unroll
    for (int q=0;q<2;++q)
      #pragma unroll
      for (int r=0;r<4;++r) psum[q][r]=0.f;
  }

  for (int ts=0; ts<SL; ++ts){
    const int cur = ts & 1;
    f16* hc = hbuf + cur*4096;
    f16* hn = hbuf + (cur^1)*4096;

    // stage next-step inputs into the free LDS half (async; drained by the
    // end-of-step __syncthreads vmcnt(0))
    if (MODE==0){
      if (tid<16 && ts+1<SL){
        const int t = slice*SL + ts + 1;   // >=1 always
        xb[(cur^1)*16 + tid] = seq[(size_t)(t-1)*BB + b0 + tid];
      }
    } else {
      if (ts+1 < SL){
        const char* gsrc = (const char*)gi_src + (size_t)(ts+1)*786432u;
        char* gdst = (char*)gib + (cur^1)*24576;
        #pragma unroll
        for (int k=0;k<3;++k){
          const int c = wid*3 + k;
          gload_lds16(gsrc + c*1024 + (lane<<4), gdst + c*1024);
        }
      }
    }
    // mask output for previous step (reads other buffer of mred; race-free)
    if (MODE==1){
      if (tid<16 && ts>0){
        float v = mlin_b[0];
        #pragma unroll
        for (int w=0;w<8;++w) v += mred[(cur^1)*128 + w*16 + tid];
        out_mask[(size_t)(slice*SL + ts-1)*BB + b0 + tid] = v;
      }
    }

    float mpart[4] = {0.f,0.f,0.f,0.f};
    #pragma unroll
    for (int q=0;q<2;++q){
      const int j = (wid*2+q)*16 + l15;
      f32x4 a0 = {cr[q],cr[q],cr[q],cr[q]};
      f32x4 a1 = {cz[q],cz[q],cz[q],cz[q]};
      f32x4 a2 = {cnh[q],cnh[q],cnh[q],cnh[q]};
      #pragma unroll
      for (int ks=0;ks<8;++ks){
        const f16x8 a = *(const f16x8*)(hc + l15*256 + ((((ks*4+lhi) ^ (l15&7)))<<3));
        a0 = __builtin_amdgcn_mfma_f32_16x16x32_f16(a, __builtin_bit_cast(f16x8, wf[q][0][ks]), a0, 0,0,0);
        a1 = __builtin_amdgcn_mfma_f32_16x16x32_f16(a, __builtin_bit_cast(f16x8, wf[q][1][ks]), a1, 0,0,0);
        a2 = __builtin_amdgcn_mfma_f32_16x16x32_f16(a, __builtin_bit_cast(f16x8, wf[q][2][ks]), a2, 0,0,0);
      }
      float gir[4], giz[4], gin[4];
      if (MODE==0){
        #pragma unroll
        for (int r=0;r<4;++r){
          const float x = xb[cur*16 + bi0 + r];
          gir[r]=x*wr_[q]; giz[r]=x*wz_[q]; gin[r]=x*wn_[q];
        }
      } else {
        const f16* gb = gib + cur*12288;
        const f16x4 g0v = *(const f16x4*)(gb + j*16 + bi0);
        const f16x4 g1v = *(const f16x4*)(gb + (256+j)*16 + bi0);
        const f16x4 g2v = *(const f16x4*)(gb + (512+j)*16 + bi0);
        #pragma unroll
        for (int r=0;r<4;++r){ gir[r]=(float)g0v[r]; giz[r]=(float)g1v[r]; gin[r]=(float)g2v[r]; }
      }
      #pragma unroll
      for (int r=0;r<4;++r){
        const int sz = hswz(bi0+r, j);
        const float hprev = (float)hc[sz];
        const float rr = sigf(gir[r] + a0[r]);
        const float zz = sigf(giz[r] + a1[r]);
        const float nn = tanh_(gin[r] + cni[q] + rr*a2[r]);
        const float h  = (1.f-zz)*nn + zz*hprev;
        hn[sz] = (f16)h;
        if (MODE==0) he_buf[((size_t)ts*BB + (b0+bi0+r))*HH + j] = (f16)h;
        if (MODE==1) mpart[r] += h*mw[q];
        if (MODE==2) psum[q][r] += h;
      }
    }
    if (MODE==1){
      #pragma unroll
      for (int m=1;m<16;m<<=1){
        #pragma unroll
        for (int r=0;r<4;++r) mpart[r] += __shfl_xor(mpart[r], m, 64);
      }
      if (l15==0){
        #pragma unroll
        for (int r=0;r<4;++r) mred[cur*128 + wid*16 + bi0 + r] = mpart[r];
      }
    }
    __syncthreads();
  }

  // final mask row
  if (MODE==1 && tid<16){
    float v = mlin_b[0];
    #pragma unroll
    for (int w=0;w<8;++w) v += mred[((SL-1)&1)*128 + w*16 + tid];
    out_mask[(size_t)(slice*SL + SL-1)*BB + b0 + tid] = v;
  }
  // h state writeback from final buffer
  {
    const f16* hf = hbuf + (SL&1)*4096;
    #pragma unroll
    for (int q=0;q<2;++q){
      const int j = (wid*2+q)*16 + l15;
      #pragma unroll
      for (int r=0;r<4;++r)
        h_state[(size_t)(b0+bi0+r)*256 + j] = hf[hswz(bi0+r, j)];
    }
  }
  if (MODE==2){
    #pragma unroll
    for (int q=0;q<2;++q){
      const int j = (wid*2+q)*16 + l15;
      #pragma unroll
      for (int r=0;r<4;++r){
        const size_t idx = (size_t)(b0+bi0+r)*256 + j;
        hpsum[idx] = hpsum[idx] + psum[q][r];
      }
    }
  }
}

// combined launcher kernel: blocks [0,n_dec) = decoders (16 mdec + 16 pdec),
// blocks [n_dec, n_dec+16) = encoder for slice enc_slice.
// amdgpu_waves_per_eu(2,2): cap occupancy at 2 waves/SIMD so the register
// allocator may use the full 256 VGPR/wave (the WG owns the whole CU RF).
__global__ __attribute__((amdgpu_flat_work_group_size(512,512), amdgpu_waves_per_eu(2,2)))
void rec_kernel(
  const float* __restrict__ seq, const float* __restrict__ dpad,
  const float* __restrict__ enc_wih, const float* __restrict__ enc_bih, const float* __restrict__ enc_bhh,
  const float* __restrict__ mdec_bih, const float* __restrict__ mdec_bhh,
  const float* __restrict__ pdec_bih, const float* __restrict__ pdec_bhh,
  const float* __restrict__ mlin_w, const float* __restrict__ mlin_b,
  const f16* __restrict__ wfrag_enc, const f16* __restrict__ wfrag_m, const f16* __restrict__ wfrag_p,
  f16* __restrict__ he_st, f16* __restrict__ hm_st, f16* __restrict__ hp_st,
  f16* __restrict__ he_buf, const f16* __restrict__ gi_buf,
  float* __restrict__ hpsum, float* __restrict__ out_mask,
  int dec_slice, int enc_slice, int n_dec, int SL)
{
  __shared__ __align__(16) unsigned char smem[16384 + 49152 + 128 + 1024];
  const int bid = blockIdx.x;
  if (bid < n_dec){
    const int rec = bid >> 4, bt = bid & 15;
    const f16* gsrc = gi_buf + ((size_t)bt*1536 + (size_t)rec*768)*16;
    if (rec==0)
      gru_run<1>(bt, dec_slice, SL, wfrag_m, mdec_bih, mdec_bhh, nullptr, nullptr, nullptr,
                 gsrc, hm_st, nullptr, mlin_w, mlin_b, out_mask, nullptr, smem);
    else
      gru_run<2>(bt, dec_slice, SL, wfrag_p, pdec_bih, pdec_bhh, nullptr, nullptr, nullptr,
                 gsrc, hp_st, nullptr, nullptr, nullptr, nullptr, hpsum, smem);
  } else {
    const int bt = bid - n_dec;
    gru_run<0>(bt, enc_slice, SL, wfrag_enc, enc_bih, enc_bhh, enc_wih, seq, dpad,
               nullptr, he_st, he_buf, nullptr, nullptr, nullptr, nullptr, smem);
  }
}

// =====================================================================
// GI: gi[t][b][n] = he[t][b][:] . w_ih_cat[n][:]  (both decoders, n<768 mdec)
// grid = SL*4 blocks (ts, batch-quarter), 256 threads
// =====================================================================
__global__ __launch_bounds__(256,4) void gi_kernel(
  const f16* __restrict__ he_buf, const f16* __restrict__ wfrag_gi,
  f16* __restrict__ gi_buf)
{
  const int ts = blockIdx.x >> 2;
  const int bq = blockIdx.x & 3;
  const int tid = threadIdx.x, lane = tid&63, wid = tid>>6;
  const int l15 = lane&15, lhi = lane>>4;
  __shared__ f16 het[64*264];
  {
    const uint4* src = (const uint4*)(he_buf + ((size_t)ts*BB + bq*64)*HH);
    uint4* dst = (uint4*)het;
    #pragma unroll
    for (int k=0;k<8;++k){
      const int i = tid + k*256;                 // 2048 uint4 = 64 rows x 32
      dst[(i>>5)*33 + (i&31)] = src[i];
    }
  }
  __syncthreads();
  for (int mi=0; mi<24; ++mi){
    const int mt = wid*24 + mi;
    f32x4 acc[4] = {{0,0,0,0},{0,0,0,0},{0,0,0,0},{0,0,0,0}};
    #pragma unroll
    for (int ks=0;ks<8;++ks){
      const f16x8 a = *(const f16x8*)(wfrag_gi + ((size_t)(mt*8+ks)*64 + lane)*8);
      #pragma unroll
      for (int bt=0;bt<4;++bt){
        const f16x8 b = *(const f16x8*)(het + (bt*16+l15)*264 + ks*32 + lhi*8);
        acc[bt] = __builtin_amdgcn_mfma_f32_16x16x32_f16(a, b, acc[bt], 0,0,0);
      }
    }
    #pragma unroll
    for (int bt=0;bt<4;++bt){
      const int btg = bq*4 + bt;
      const size_t base = (((size_t)ts*16 + btg)*1536 + (size_t)mt*16 + lhi*4)*16 + l15;
      #pragma unroll
      for (int r=0;r<4;++r) gi_buf[base + (size_t)r*16] = (f16)acc[bt][r];
    }
  }
}

// =====================================================================
// PRED: pred[b][p] = (hpsum[b]/512) . plin_w[p] + plin_b[p]
// =====================================================================
__global__ __launch_bounds__(256,1) void pred_kernel(
  const float* __restrict__ hpsum, const float* __restrict__ plin_w,
  const float* __restrict__ plin_b, float* __restrict__ out)
{
  __shared__ float hs[256];
  const int p = threadIdx.x;
  const float bias = plin_b[p];
  for (int bb=0; bb<4; ++bb){
    const int b = blockIdx.x*4 + bb;
    __syncthreads();
    hs[p] = hpsum[(size_t)b*256 + p];
    __syncthreads();
    float acc = 0.f;
    const float4* wrow = (const float4*)(plin_w + (size_t)p*256);
    #pragma unroll 4
    for (int k4=0;k4<64;++k4){
      const float4 w = wrow[k4];
      acc += hs[k4*4+0]*w.x + hs[k4*4+1]*w.y + hs[k4*4+2]*w.z + hs[k4*4+3]*w.w;
    }
    out[131072 + (size_t)b*256 + p] = acc*(1.f/512.f) + bias;
  }
}

// =====================================================================
extern "C" void kernel_launch(void* const* d_in, const int* in_sizes, int n_in,
                              void* d_out, int out_size, void* d_ws, size_t ws_size,
                              hipStream_t stream)
{
  const float* seq      = (const float*)d_in[0];
  const float* dpad     = (const float*)d_in[1];
  const float* h0e      = (const float*)d_in[2];
  const float* h0m      = (const float*)d_in[3];
  const float* h0p      = (const float*)d_in[4];
  const float* enc_wih  = (const float*)d_in[5];
  const float* enc_whh  = (const float*)d_in[6];
  const float* enc_bih  = (const float*)d_in[7];
  const float* enc_bhh  = (const float*)d_in[8];
  const float* mdec_wih = (const float*)d_in[9];
  const float* mdec_whh = (const float*)d_in[10];
  const float* mdec_bih = (const float*)d_in[11];
  const float* mdec_bhh = (const float*)d_in[12];
  const float* mlin_w   = (const float*)d_in[13];
  const float* mlin_b   = (const float*)d_in[14];
  const float* pdec_wih = (const float*)d_in[15];
  const float* pdec_whh = (const float*)d_in[16];
  const float* pdec_bih = (const float*)d_in[17];
  const float* pdec_bhh = (const float*)d_in[18];
  const float* plin_w   = (const float*)d_in[19];
  const float* plin_b   = (const float*)d_in[20];
  float* out = (float*)d_out;

  char* ws = (char*)d_ws;
  f16* wfrag_enc = (f16*)(ws + O_WFRAG_ENC);
  f16* wfrag_m   = (f16*)(ws + O_WFRAG_M);
  f16* wfrag_p   = (f16*)(ws + O_WFRAG_P);
  f16* wfrag_gi  = (f16*)(ws + O_WFRAG_GI);
  f16* he_st     = (f16*)(ws + O_HE_ST);
  f16* hm_st     = (f16*)(ws + O_HM_ST);
  f16* hp_st     = (f16*)(ws + O_HP_ST);
  float* hpsum   = (float*)(ws + O_HPSUM);

  int SL = 64;  // time-slice length; shrink to fit workspace
  while (SL > 1 && (size_t)O_DYN + (size_t)SL*DYN_PER_STEP > ws_size) SL >>= 1;
  const int S = TT / SL;
  f16* he_buf = (f16*)(ws + O_DYN);
  f16* gi_buf = (f16*)(ws + O_DYN + (size_t)SL*131072u);

  prep_kernel<<<dim3(4096), dim3(256), 0, stream>>>(
      enc_whh, mdec_whh, pdec_whh, mdec_wih, pdec_wih, h0e, h0m, h0p,
      wfrag_enc, wfrag_m, wfrag_p, wfrag_gi, he_st, hm_st, hp_st, hpsum);

  // encoder slice 0 (no decoders yet)
  rec_kernel<<<dim3(16), dim3(512), 0, stream>>>(
      seq, dpad, enc_wih, enc_bih, enc_bhh, mdec_bih, mdec_bhh, pdec_bih, pdec_bhh,
      mlin_w, mlin_b, wfrag_enc, wfrag_m, wfrag_p, he_st, hm_st, hp_st,
      he_buf, gi_buf, hpsum, out, 0, 0, 0, SL);
  gi_kernel<<<dim3(SL*4), dim3(256), 0, stream>>>(he_buf, wfrag_gi, gi_buf);

  for (int s=0; s<S; ++s){
    const int has_enc = (s+1 < S);
    rec_kernel<<<dim3(has_enc?48:32), dim3(512), 0, stream>>>(
        seq, dpad, enc_wih, enc_bih, enc_bhh, mdec_bih, mdec_bhh, pdec_bih, pdec_bhh,
        mlin_w, mlin_b, wfrag_enc, wfrag_m, wfrag_p, he_st, hm_st, hp_st,
        he_buf, gi_buf, hpsum, out, s, s+1, 32, SL);
    if (has_enc)
      gi_kernel<<<dim3(SL*4), dim3(256), 0, stream>>>(he_buf, wfrag_gi, gi_buf);
  }

  pred_kernel<<<dim3(64), dim3(256), 0, stream>>>(hpsum, plin_w, plin_b, out);
}